// Round 1
// baseline (2116.422 us; speedup 1.0000x reference)
//
#include <hip/hip_runtime.h>
#include <stdint.h>

// ---------------- types ----------------
typedef _Float16 half_t;
typedef _Float16 half8 __attribute__((ext_vector_type(8)));
typedef _Float16 half4 __attribute__((ext_vector_type(4)));
typedef float f32x16 __attribute__((ext_vector_type(16)));
typedef float f32x4  __attribute__((ext_vector_type(4)));

// ---------------- problem constants ----------------
#define OBS_D 128
#define ACT_D 32
#define IN_D  160            // OBS_D + ACT_D
#define H_D   512
#define T_H   63             // horizon
#define NROWS 2048           // B*N = 32*64
#define KTOT  672            // IN_D + H_D
#define KT_ALL 42            // KTOT/16
#define KT_X   10            // IN_D/16
#define KT_H   32            // H_D/16
#define NT_ALL 48            // 1536/32
#define RB     32            // rows per block in recurrent kernel
#define NBLK   64            // NROWS/RB
#define PRED_ELEMS (NROWS*T_H*OBS_D)   // 16515072 ; hs starts here in d_out

#define ZERO16 {0.f,0.f,0.f,0.f,0.f,0.f,0.f,0.f,0.f,0.f,0.f,0.f,0.f,0.f,0.f,0.f}
#define MFMA16 __builtin_amdgcn_mfma_f32_32x32x16_f16

__device__ __forceinline__ float sigm(float x) {
    return __builtin_amdgcn_rcpf(1.0f + __expf(-x));
}
__device__ __forceinline__ float tanh_f(float x) {
    // robust for large |x|: expf->inf -> rcp->0 -> -1 ; expf->0 -> 2-1 = +1
    return 2.0f * __builtin_amdgcn_rcpf(1.0f + __expf(-2.0f * x)) - 1.0f;
}

// ============================================================================
// pack_w: W = [w_ih | w_hh] (gates x 672) and w_dec (128 x 512) -> fp16
// B-fragment order for mfma_32x32x16: frag[nt][kt][lane][j] = W[n][k],
//   n = nt*32 + (lane&31), k = kt*16 + (lane>>5)*8 + j
// ============================================================================
__global__ void pack_w(const float* __restrict__ w_ih, const float* __restrict__ w_hh,
                       const float* __restrict__ w_dec,
                       half_t* __restrict__ wpack, half_t* __restrict__ wdpack) {
    int idx = blockIdx.x * 256 + threadIdx.x;
    int lane = idx & 63;
    int m = lane & 31;
    int khalf = lane >> 5;
    if (idx < NT_ALL * KT_ALL * 64) {
        int kt = (idx >> 6) % KT_ALL;
        int nt = idx / (64 * KT_ALL);
        int n = nt * 32 + m;
        int k0 = kt * 16 + khalf * 8;
        half8 o;
        #pragma unroll
        for (int j = 0; j < 8; ++j) {
            int k = k0 + j;
            float v = (k < IN_D) ? w_ih[(size_t)n * IN_D + k]
                                 : w_hh[(size_t)n * H_D + (k - IN_D)];
            o[j] = (half_t)v;
        }
        *(half8*)(wpack + (size_t)idx * 8) = o;
    } else {
        int r = idx - NT_ALL * KT_ALL * 64;   // < 8192
        int kt = (r >> 6) % 32;
        int nt = r / (64 * 32);
        int n = nt * 32 + m;                  // output col (0..127)
        int k0 = kt * 16 + khalf * 8;
        half8 o;
        #pragma unroll
        for (int j = 0; j < 8; ++j) o[j] = (half_t)w_dec[(size_t)n * H_D + k0 + j];
        *(half8*)(wdpack + (size_t)r * 8) = o;
    }
}

// ============================================================================
// pack_x: x = concat(obs, act) -> fp16 A-fragment order
// xfrag[rb][t][kt][lane][j] = x[t][row][k], row = rb*32 + (lane&31),
//   k = kt*16 + (lane>>5)*8 + j
// ============================================================================
__global__ void pack_x(const float* __restrict__ obs, const float* __restrict__ act,
                       half_t* __restrict__ xfrag) {
    int idx = blockIdx.x * 256 + threadIdx.x;
    int lane = idx & 63;
    int kt = (idx >> 6) % KT_X;
    int t  = (idx / (64 * KT_X)) % T_H;
    int rb = idx / (64 * KT_X * T_H);
    int m = lane & 31;
    int row = rb * RB + m;
    int b = row >> 6, nn = row & 63;
    int k0 = kt * 16 + (lane >> 5) * 8;
    const float* ob = obs + (((size_t)(b * 64 + t)) * 64 + nn) * OBS_D;  // T=64 in input!
    const float* ac = act + (((size_t)(b * 64 + t)) * 64 + nn) * ACT_D;
    half8 o;
    #pragma unroll
    for (int j = 0; j < 8; ++j) {
        int k = k0 + j;
        float v = (k < OBS_D) ? ob[k] : ac[k - OBS_D];
        o[j] = (half_t)v;
    }
    *(half8*)(xfrag + (size_t)idx * 8) = o;
}

// ============================================================================
// gru_main: 64 blocks x 1024 threads (16 waves). Block rb owns rows rb*32..+32.
// Wave w owns ONE dim-group d = [w*32, w*32+32): r(d), z(d), n(d) ->
//   4 accumulators (ar, az, ai, ah) = 64 VGPR; h fp32 in 16 regs.
// x-part A-frags are read directly from global (L1-broadcast across waves);
// h-part A-frags live in double-buffered LDS -> ONE barrier per step.
// Biases folded into accumulator init.
// ============================================================================
__global__ __launch_bounds__(1024, 4) void gru_main(
        const half_t* __restrict__ wpack, const half_t* __restrict__ xfrag,
        const float* __restrict__ b_ih, const float* __restrict__ b_hh,
        float* __restrict__ out) {
    __shared__ __align__(16) half_t Abuf[2 * KT_H * 512];   // 65536 B, double-buffered h

    const int tid = threadIdx.x;
    const int w = tid >> 6;          // 0..15
    const int lane = tid & 63;
    const int col = lane & 31;
    const int mbase = (lane >> 5) * 4;
    const int rb = blockIdx.x;

    // zero both h buffers (t=0 reads zeros; every later step fully overwrites)
    {
        uint4 zz = {0u, 0u, 0u, 0u};
        uint4* z4 = (uint4*)Abuf;
        #pragma unroll
        for (int i = 0; i < 4; ++i) z4[tid + i * 1024] = zz;
    }

    // per-lane constants
    const int d = w * 32 + col;               // this wave's h-dim
    const float br = b_ih[d] + b_hh[d];
    const float bz = b_ih[512 + d] + b_hh[512 + d];
    const float bi = b_ih[1024 + d];
    const float bh = b_hh[1024 + d];

    // B-fragment stream bases (element offsets; +512 per kt)
    const half_t* wr = wpack + ((size_t)(w)      * KT_ALL) * 512 + lane * 8;
    const half_t* wz = wpack + ((size_t)(16 + w) * KT_ALL) * 512 + lane * 8;
    const half_t* wn = wpack + ((size_t)(32 + w) * KT_ALL) * 512 + lane * 8;
    const half_t* whr = wr + (size_t)KT_X * 512;
    const half_t* whz = wz + (size_t)KT_X * 512;
    const half_t* whn = wn + (size_t)KT_X * 512;

    const int b_out = rb >> 1;
    const int nn_base = (rb & 1) << 5;

    float h[16];
    #pragma unroll
    for (int i = 0; i < 16; ++i) h[i] = 0.0f;

    // scatter-write constants (C/D reg -> A-frag LDS position), local h-kt 0..31
    const int lp = 32 * ((col >> 3) & 1);
    const int jj = col & 7;
    const int ktb = 2 * w + (col >> 4);

    const half_t* xb = xfrag + (size_t)rb * T_H * (KT_X * 512) + lane * 8;
    float* hbase = out + (size_t)PRED_ELEMS
                 + ((size_t)b_out * T_H) * (64 * 512) + (size_t)nn_base * 512 + d;

    int p = 0;
    __syncthreads();

    for (int t = 0; t < T_H; ++t) {
        f32x16 ar, az, ai, ah;
        #pragma unroll
        for (int i = 0; i < 16; ++i) { ar[i] = br; az[i] = bz; ai[i] = bi; ah[i] = bh; }

        // x part (global, L1-served): r, z, gi_n
        #pragma unroll 2
        for (int kt = 0; kt < KT_X; ++kt) {
            half8 a = *(const half8*)(xb + kt * 512);
            ar = MFMA16(a, *(const half8*)(wr + kt * 512), ar, 0, 0, 0);
            az = MFMA16(a, *(const half8*)(wz + kt * 512), az, 0, 0, 0);
            ai = MFMA16(a, *(const half8*)(wn + kt * 512), ai, 0, 0, 0);
        }
        // h part (LDS buffer p): r, z, gh_n
        const half8* Af = (const half8*)(Abuf + (size_t)p * (KT_H * 512)) + lane;
        #pragma unroll 4
        for (int kt = 0; kt < KT_H; ++kt) {
            half8 a = Af[kt * 64];
            ar = MFMA16(a, *(const half8*)(whr + kt * 512), ar, 0, 0, 0);
            az = MFMA16(a, *(const half8*)(whz + kt * 512), az, 0, 0, 0);
            ah = MFMA16(a, *(const half8*)(whn + kt * 512), ah, 0, 0, 0);
        }

        // epilogue: gates -> h update -> global hs store + LDS scatter to buf p^1
        float* hp = hbase + (size_t)t * (64 * 512);
        half_t* Ab1 = Abuf + (size_t)(p ^ 1) * (KT_H * 512);
        #pragma unroll
        for (int r = 0; r < 16; ++r) {
            int m = (r & 3) + 8 * (r >> 2) + mbase;   // C/D row (verified mapping)
            float rr = sigm(ar[r]);
            float zz2 = sigm(az[r]);
            float nn2 = tanh_f(ai[r] + rr * ah[r]);
            float hv = (1.0f - zz2) * nn2 + zz2 * h[r];
            h[r] = hv;
            hp[(size_t)m * 512] = hv;
            Ab1[ktb * 512 + (m + lp) * 8 + jj] = (half_t)hv;
        }

        xb += KT_X * 512;
        __syncthreads();   // scatter to p^1 visible; readers of p are done
        p ^= 1;
    }
}

// ============================================================================
// dec_k: preds = hs @ w_dec^T + b_dec.  4032 blocks x 256 threads (4 waves).
// Block: 32 rows; wave w: output cols [w*32, w*32+32).
// ============================================================================
#define DPAD 520   // fp16 row stride (pad 512 -> 520 to break 32-way LDS conflicts)
__global__ __launch_bounds__(256) void dec_k(
        const float* __restrict__ hs, const half_t* __restrict__ wdpack,
        const float* __restrict__ b_dec, float* __restrict__ preds) {
    __shared__ __align__(16) half_t Ab[32 * DPAD];   // 33280 B
    const int tid = threadIdx.x, w = tid >> 6, lane = tid & 63;
    const size_t row0 = (size_t)blockIdx.x * 32;

    // stage 32x512 fp32 -> fp16 row-major (padded) in LDS, coalesced
    const float* src = hs + row0 * 512;
    #pragma unroll
    for (int c = 0; c < 16; ++c) {
        int f = c * 1024 + tid * 4;
        f32x4 v = *(const f32x4*)(src + f);
        int m = f >> 9, colc = f & 511;
        half4 o;
        o[0] = (half_t)v[0]; o[1] = (half_t)v[1]; o[2] = (half_t)v[2]; o[3] = (half_t)v[3];
        *(half4*)(Ab + m * DPAD + colc) = o;
    }
    __syncthreads();

    f32x16 acc = ZERO16;
    const half_t* wd = wdpack + ((size_t)w * 32) * 512 + lane * 8;
    const int mA = lane & 31, k0 = (lane >> 5) * 8;
    #pragma unroll 4
    for (int kt = 0; kt < 32; ++kt) {
        half8 a = *(const half8*)(Ab + mA * DPAD + kt * 16 + k0);
        half8 b = *(const half8*)(wd + kt * 512);
        acc = MFMA16(a, b, acc, 0, 0, 0);
    }
    const int colD = w * 32 + (lane & 31);
    const float bd = b_dec[colD];
    #pragma unroll
    for (int r = 0; r < 16; ++r) {
        int m = (r & 3) + 8 * (r >> 2) + 4 * (lane >> 5);
        preds[(row0 + m) * 128 + colD] = acc[r] + bd;
    }
}

// ============================================================================
extern "C" void kernel_launch(void* const* d_in, const int* in_sizes, int n_in,
                              void* d_out, int out_size, void* d_ws, size_t ws_size,
                              hipStream_t stream) {
    const float* obs   = (const float*)d_in[0];
    const float* act   = (const float*)d_in[1];
    const float* w_ih  = (const float*)d_in[2];
    const float* w_hh  = (const float*)d_in[3];
    const float* b_ih  = (const float*)d_in[4];
    const float* b_hh  = (const float*)d_in[5];
    const float* w_dec = (const float*)d_in[6];
    const float* b_dec = (const float*)d_in[7];
    // d_in[8] = horizon (fixed 63; compiled in)
    float* out = (float*)d_out;

    // workspace layout (fp16 elements): wpack | wdpack | xfrag  ~= 41.5 MB
    half_t* wpack  = (half_t*)d_ws;                          // 48*42*512  = 1032192
    half_t* wdpack = wpack + (size_t)NT_ALL * KT_ALL * 512;  // 4*32*512 = 65536
    half_t* xfrag  = wdpack + (size_t)4 * 32 * 512;          // 64*63*5120 = 20643840

    hipLaunchKernelGGL(pack_w, dim3(536), dim3(256), 0, stream,
                       w_ih, w_hh, w_dec, wpack, wdpack);
    hipLaunchKernelGGL(pack_x, dim3(10080), dim3(256), 0, stream, obs, act, xfrag);
    hipLaunchKernelGGL(gru_main, dim3(NBLK), dim3(1024), 0, stream,
                       wpack, xfrag, b_ih, b_hh, out);
    hipLaunchKernelGGL(dec_k, dim3(NROWS * T_H / 32), dim3(256), 0, stream,
                       out + (size_t)PRED_ELEMS, wdpack, b_dec, out);
}

// Round 2
// 1601.368 us; speedup vs baseline: 1.3216x; 1.3216x over previous
//
#include <hip/hip_runtime.h>
#include <stdint.h>

// ---------------- types ----------------
typedef _Float16 half_t;
typedef _Float16 half8 __attribute__((ext_vector_type(8)));
typedef _Float16 half4 __attribute__((ext_vector_type(4)));
typedef float f32x16 __attribute__((ext_vector_type(16)));
typedef float f32x4  __attribute__((ext_vector_type(4)));

// ---------------- problem constants ----------------
#define OBS_D 128
#define ACT_D 32
#define IN_D  160            // OBS_D + ACT_D
#define H_D   512
#define T_H   63             // horizon
#define NROWS 2048           // B*N = 32*64
#define KTOT  672            // IN_D + H_D
#define KT_ALL 42            // KTOT/16
#define KT_X   10            // IN_D/16
#define KT_H   32            // H_D/16
#define NT_ALL 48            // 1536/32
#define RB     32            // rows per block in recurrent kernel
#define NBLK   64            // NROWS/RB (row-groups)
#define PRED_ELEMS (NROWS*T_H*OBS_D)   // 16515072 ; hs starts here in d_out

#define ZERO16 {0.f,0.f,0.f,0.f,0.f,0.f,0.f,0.f,0.f,0.f,0.f,0.f,0.f,0.f,0.f,0.f}
#define MFMA16 __builtin_amdgcn_mfma_f32_32x32x16_f16

__device__ __forceinline__ float sigm(float x) {
    return __builtin_amdgcn_rcpf(1.0f + __expf(-x));
}
__device__ __forceinline__ float tanh_f(float x) {
    // robust for large |x|: expf->inf -> rcp->0 -> -1 ; expf->0 -> 2-1 = +1
    return 2.0f * __builtin_amdgcn_rcpf(1.0f + __expf(-2.0f * x)) - 1.0f;
}

// ============================================================================
// pack_w: W = [w_ih | w_hh] (gates x 672) and w_dec (128 x 512) -> fp16
// B-fragment order for mfma_32x32x16: frag[nt][kt][lane][j] = W[n][k],
//   n = nt*32 + (lane&31), k = kt*16 + (lane>>5)*8 + j
// ============================================================================
__global__ void pack_w(const float* __restrict__ w_ih, const float* __restrict__ w_hh,
                       const float* __restrict__ w_dec,
                       half_t* __restrict__ wpack, half_t* __restrict__ wdpack) {
    int idx = blockIdx.x * 256 + threadIdx.x;
    int lane = idx & 63;
    int m = lane & 31;
    int khalf = lane >> 5;
    if (idx < NT_ALL * KT_ALL * 64) {
        int kt = (idx >> 6) % KT_ALL;
        int nt = idx / (64 * KT_ALL);
        int n = nt * 32 + m;
        int k0 = kt * 16 + khalf * 8;
        half8 o;
        #pragma unroll
        for (int j = 0; j < 8; ++j) {
            int k = k0 + j;
            float v = (k < IN_D) ? w_ih[(size_t)n * IN_D + k]
                                 : w_hh[(size_t)n * H_D + (k - IN_D)];
            o[j] = (half_t)v;
        }
        *(half8*)(wpack + (size_t)idx * 8) = o;
    } else {
        int r = idx - NT_ALL * KT_ALL * 64;   // < 8192
        int kt = (r >> 6) % 32;
        int nt = r / (64 * 32);
        int n = nt * 32 + m;                  // output col (0..127)
        int k0 = kt * 16 + khalf * 8;
        half8 o;
        #pragma unroll
        for (int j = 0; j < 8; ++j) o[j] = (half_t)w_dec[(size_t)n * H_D + k0 + j];
        *(half8*)(wdpack + (size_t)r * 8) = o;
    }
}

// ============================================================================
// pack_x: x = concat(obs, act) -> fp16 A-fragment order ; also zeroes flags
// xfrag[rb][t][kt][lane][j] = x[t][row][k], row = rb*32 + (lane&31),
//   k = kt*16 + (lane>>5)*8 + j
// ============================================================================
__global__ void pack_x(const float* __restrict__ obs, const float* __restrict__ act,
                       half_t* __restrict__ xfrag, unsigned* __restrict__ flags) {
    int idx = blockIdx.x * 256 + threadIdx.x;
    if (idx < NBLK * T_H * 2)   // agent-scope (sc1) so gru_main's sc1 polls see 0
        __hip_atomic_store(&flags[idx], 0u, __ATOMIC_RELAXED, __HIP_MEMORY_SCOPE_AGENT);
    int lane = idx & 63;
    int kt = (idx >> 6) % KT_X;
    int t  = (idx / (64 * KT_X)) % T_H;
    int rb = idx / (64 * KT_X * T_H);
    int m = lane & 31;
    int row = rb * RB + m;
    int b = row >> 6, nn = row & 63;
    int k0 = kt * 16 + (lane >> 5) * 8;
    const float* ob = obs + (((size_t)(b * 64 + t)) * 64 + nn) * OBS_D;  // T=64 in input!
    const float* ac = act + (((size_t)(b * 64 + t)) * 64 + nn) * ACT_D;
    half8 o;
    #pragma unroll
    for (int j = 0; j < 8; ++j) {
        int k = k0 + j;
        float v = (k < OBS_D) ? ob[k] : ac[k - OBS_D];
        o[j] = (half_t)v;
    }
    *(half8*)(xfrag + (size_t)idx * 8) = o;
}

// ============================================================================
// gru_main: 128 blocks x 512 threads (8 waves).
//   rb = blockIdx>>1 : rows rb*32..+32 ; cb = blockIdx&1 : h-dims cb*256..+256.
// Each block streams HALF of wpack per step (1 MB) -> 2x CUs share the
// per-CU L2-BW-bound weight stream (the measured bottleneck).
// Wave w: dims d = cb*256 + w*32 + [0,32): streams r/z/n -> 4 accumulators.
// Per step: block writes its 256 h dims to global hs (agent-scope sc1, it is
// an output anyway), signals a per-(rb,t) flag, spins on partner flag, then
// stages partner's 256 dims from global into the next A-frag LDS buffer.
// Exchange addresses are fresh per step -> no stale-cache hazard on any XCD.
// ============================================================================
__global__ __launch_bounds__(512, 2) void gru_main(
        const half_t* __restrict__ wpack, const half_t* __restrict__ xfrag,
        const float* __restrict__ b_ih, const float* __restrict__ b_hh,
        float* __restrict__ out, unsigned* __restrict__ flags) {
    __shared__ __align__(16) half_t Xbuf[KT_X * 512];        // 10 KB
    __shared__ __align__(16) half_t Abuf[2 * KT_H * 512];    // 64 KB (dbuf h)

    const int tid = threadIdx.x;
    const int w = tid >> 6;            // 0..7
    const int lane = tid & 63;
    const int col = lane & 31;
    const int mbase = (lane >> 5) * 4;
    const int rb = blockIdx.x >> 1;
    const int cb = blockIdx.x & 1;

    // zero both h A-frag buffers (t=0 reads zeros)
    {
        uint4 zz = {0u, 0u, 0u, 0u};
        uint4* z4 = (uint4*)Abuf;
        #pragma unroll
        for (int i = 0; i < 8; ++i) z4[tid + i * 512] = zz;
    }
    // copy x(0)
    {
        const uint4* src = (const uint4*)(xfrag + (size_t)rb * T_H * (KT_X * 512));
        uint4* dst = (uint4*)Xbuf;
        for (int s = tid; s < KT_X * 64; s += 512) dst[s] = src[s];
    }

    // per-lane constants
    const int d = cb * 256 + w * 32 + col;    // this wave's h-dim
    const float br = b_ih[d] + b_hh[d];
    const float bz = b_ih[512 + d] + b_hh[512 + d];
    const float bi = b_ih[1024 + d];
    const float bh = b_hh[1024 + d];

    // B-fragment stream bases (element offsets; +512 per kt)
    const int ntr = cb * 8 + w;
    const half_t* wr = wpack + ((size_t)ntr        * KT_ALL) * 512 + lane * 8;
    const half_t* wz = wpack + ((size_t)(16 + ntr) * KT_ALL) * 512 + lane * 8;
    const half_t* wn = wpack + ((size_t)(32 + ntr) * KT_ALL) * 512 + lane * 8;
    const half_t* whr = wr + (size_t)KT_X * 512;
    const half_t* whz = wz + (size_t)KT_X * 512;
    const half_t* whn = wn + (size_t)KT_X * 512;

    const int b_out = rb >> 1;
    const int nn_base = (rb & 1) << 5;

    float h[16];
    #pragma unroll
    for (int i = 0; i < 16; ++i) h[i] = 0.0f;

    // scatter-write constants (C/D reg -> A-frag LDS position); global k = d
    const int lp = 32 * ((col >> 3) & 1);
    const int jj = col & 7;
    const int ktb = d >> 4;               // includes cb*16 offset

    float* hbase = out + (size_t)PRED_ELEMS
                 + ((size_t)b_out * T_H) * (64 * 512) + (size_t)nn_base * 512 + d;

    int p = 0;
    __syncthreads();

    for (int t = 0; ; ++t) {
        f32x16 ar, az, ai, ah;
        #pragma unroll
        for (int i = 0; i < 16; ++i) { ar[i] = br; az[i] = bz; ai[i] = bi; ah[i] = bh; }

        // x part: r, z, gi_n
        const half8* Xf = (const half8*)Xbuf + lane;
        #pragma unroll 2
        for (int kt = 0; kt < KT_X; ++kt) {
            half8 a = Xf[kt * 64];
            ar = MFMA16(a, *(const half8*)(wr + kt * 512), ar, 0, 0, 0);
            az = MFMA16(a, *(const half8*)(wz + kt * 512), az, 0, 0, 0);
            ai = MFMA16(a, *(const half8*)(wn + kt * 512), ai, 0, 0, 0);
        }
        // h part (LDS buffer p): r, z, gh_n
        const half8* Af = (const half8*)(Abuf + (size_t)p * (KT_H * 512)) + lane;
        #pragma unroll 2
        for (int kt = 0; kt < KT_H; ++kt) {
            half8 a = Af[kt * 64];
            ar = MFMA16(a, *(const half8*)(whr + kt * 512), ar, 0, 0, 0);
            az = MFMA16(a, *(const half8*)(whz + kt * 512), az, 0, 0, 0);
            ah = MFMA16(a, *(const half8*)(whn + kt * 512), ah, 0, 0, 0);
        }

        // epilogue: gates -> h update -> global hs store (sc1) + own scatter
        float* hp = hbase + (size_t)t * (64 * 512);
        half_t* Ab1 = Abuf + (size_t)(p ^ 1) * (KT_H * 512);
        #pragma unroll
        for (int r = 0; r < 16; ++r) {
            int m = (r & 3) + 8 * (r >> 2) + mbase;   // C/D row (verified mapping)
            float rr = sigm(ar[r]);
            float zz2 = sigm(az[r]);
            float nn2 = tanh_f(ai[r] + rr * ah[r]);
            float hv = (1.0f - zz2) * nn2 + zz2 * h[r];
            h[r] = hv;
            __hip_atomic_store(hp + (size_t)m * 512, hv,
                               __ATOMIC_RELAXED, __HIP_MEMORY_SCOPE_AGENT);
            Ab1[ktb * 512 + (m + lp) * 8 + jj] = (half_t)hv;
        }

        if (t == T_H - 1) break;

        __syncthreads();     // A: every wave's hs stores drained (vmcnt 0)

        // ---- pairwise rendezvous ----
        unsigned* fl = flags + (((size_t)rb * T_H) + t) * 2;
        if (tid == 0) {
            __hip_atomic_store(fl + cb, 1u, __ATOMIC_RELEASE, __HIP_MEMORY_SCOPE_AGENT);
            int guard = 0;
            while (__hip_atomic_load(fl + (cb ^ 1),
                                     __ATOMIC_RELAXED, __HIP_MEMORY_SCOPE_AGENT) == 0u) {
                __builtin_amdgcn_s_sleep(4);
                if (++guard > (1 << 20)) break;   // fail loud (absmax), never hang
            }
        }
        __syncthreads();     // B: partner h(t) is in L3

        // stage partner's 256 dims -> Ab1 (addresses fresh this step on every
        // cache on this XCD -> plain loads cannot hit stale lines)
        {
            const float* ph = out + (size_t)PRED_ELEMS
                + ((size_t)b_out * T_H + t) * (64 * 512)
                + (size_t)nn_base * 512 + (cb ^ 1) * 256;
            #pragma unroll
            for (int i = tid; i < 2048; i += 512) {      // 2048 float4 = 32 KB
                int m = i >> 6;
                int c4 = (i & 63) * 4;
                f32x4 v = *(const f32x4*)(ph + (size_t)m * 512 + c4);
                int k = (cb ^ 1) * 256 + c4;
                int kt = k >> 4, kh = (k >> 3) & 1, j0 = k & 7;
                half4 o;
                o[0] = (half_t)v[0]; o[1] = (half_t)v[1];
                o[2] = (half_t)v[2]; o[3] = (half_t)v[3];
                *(half4*)(Ab1 + kt * 512 + kh * 256 + m * 8 + j0) = o;
            }
            // copy x(t+1)
            const uint4* src = (const uint4*)(xfrag +
                ((size_t)rb * T_H + (t + 1)) * (size_t)(KT_X * 512));
            uint4* dst = (uint4*)Xbuf;
            for (int s = tid; s < KT_X * 64; s += 512) dst[s] = src[s];
        }
        __syncthreads();     // C: staging visible
        p ^= 1;
    }
}

// ============================================================================
// dec_k: preds = hs @ w_dec^T + b_dec.  4032 blocks x 256 threads (4 waves).
// Block: 32 rows; wave w: output cols [w*32, w*32+32).
// ============================================================================
#define DPAD 520   // fp16 row stride (pad 512 -> 520 to break 32-way LDS conflicts)
__global__ __launch_bounds__(256) void dec_k(
        const float* __restrict__ hs, const half_t* __restrict__ wdpack,
        const float* __restrict__ b_dec, float* __restrict__ preds) {
    __shared__ __align__(16) half_t Ab[32 * DPAD];   // 33280 B
    const int tid = threadIdx.x, w = tid >> 6, lane = tid & 63;
    const size_t row0 = (size_t)blockIdx.x * 32;

    // stage 32x512 fp32 -> fp16 row-major (padded) in LDS, coalesced
    const float* src = hs + row0 * 512;
    #pragma unroll
    for (int c = 0; c < 16; ++c) {
        int f = c * 1024 + tid * 4;
        f32x4 v = *(const f32x4*)(src + f);
        int m = f >> 9, colc = f & 511;
        half4 o;
        o[0] = (half_t)v[0]; o[1] = (half_t)v[1]; o[2] = (half_t)v[2]; o[3] = (half_t)v[3];
        *(half4*)(Ab + m * DPAD + colc) = o;
    }
    __syncthreads();

    f32x16 acc = ZERO16;
    const half_t* wd = wdpack + ((size_t)w * 32) * 512 + lane * 8;
    const int mA = lane & 31, k0 = (lane >> 5) * 8;
    #pragma unroll 4
    for (int kt = 0; kt < 32; ++kt) {
        half8 a = *(const half8*)(Ab + mA * DPAD + kt * 16 + k0);
        half8 b = *(const half8*)(wd + kt * 512);
        acc = MFMA16(a, b, acc, 0, 0, 0);
    }
    const int colD = w * 32 + (lane & 31);
    const float bd = b_dec[colD];
    #pragma unroll
    for (int r = 0; r < 16; ++r) {
        int m = (r & 3) + 8 * (r >> 2) + 4 * (lane >> 5);
        preds[(row0 + m) * 128 + colD] = acc[r] + bd;
    }
}

// ============================================================================
extern "C" void kernel_launch(void* const* d_in, const int* in_sizes, int n_in,
                              void* d_out, int out_size, void* d_ws, size_t ws_size,
                              hipStream_t stream) {
    const float* obs   = (const float*)d_in[0];
    const float* act   = (const float*)d_in[1];
    const float* w_ih  = (const float*)d_in[2];
    const float* w_hh  = (const float*)d_in[3];
    const float* b_ih  = (const float*)d_in[4];
    const float* b_hh  = (const float*)d_in[5];
    const float* w_dec = (const float*)d_in[6];
    const float* b_dec = (const float*)d_in[7];
    // d_in[8] = horizon (fixed 63; compiled in)
    float* out = (float*)d_out;

    // workspace layout (fp16 elements): wpack | wdpack | xfrag | flags ~= 43.5 MB
    half_t* wpack  = (half_t*)d_ws;                          // 48*42*512  = 1032192
    half_t* wdpack = wpack + (size_t)NT_ALL * KT_ALL * 512;  // 4*32*512 = 65536
    half_t* xfrag  = wdpack + (size_t)4 * 32 * 512;          // 64*63*5120 = 20643840
    unsigned* flags = (unsigned*)(xfrag + (size_t)NBLK * T_H * (KT_X * 512));

    hipLaunchKernelGGL(pack_w, dim3(536), dim3(256), 0, stream,
                       w_ih, w_hh, w_dec, wpack, wdpack);
    hipLaunchKernelGGL(pack_x, dim3(10080), dim3(256), 0, stream,
                       obs, act, xfrag, flags);
    hipLaunchKernelGGL(gru_main, dim3(NBLK * 2), dim3(512), 0, stream,
                       wpack, xfrag, b_ih, b_hh, out, flags);
    hipLaunchKernelGGL(dec_k, dim3(NROWS * T_H / 32), dim3(256), 0, stream,
                       out + (size_t)PRED_ELEMS, wdpack, b_dec, out);
}